// Round 15
// baseline (163.039 us; speedup 1.0000x reference)
//
#include <hip/hip_runtime.h>
#include <math.h>

// nodes-per-bucket = 128 (pow2). nbk = ceil(N/128) buckets (<= 512 for N<=65536).
#define NPB_SHIFT 7
#define NPB 128
#define NBK_MAX 512
#define BCAP 3584   // fixed bucket capacity; Poisson(2688) edges/bucket, 17 sigma

typedef _Float16 f16x2 __attribute__((ext_vector_type(2)));
typedef _Float16 f16x4 __attribute__((ext_vector_type(4)));
typedef float f32x4 __attribute__((ext_vector_type(4)));
union F16U { f16x2 v; unsigned int u; };

// ---------------- CSR build (fixed-capacity buckets) ----------

__global__ __launch_bounds__(1024) void k_scatter_agg(
    const int* __restrict__ src, const int* __restrict__ dst,
    const float* __restrict__ ea, int E, int nbk, int chunk,
    int* bcur, int2* __restrict__ tmp) {
  __shared__ int lcnt[NBK_MAX], lcnt2[NBK_MAX], lbase[NBK_MAX];
  int t = threadIdx.x;
  for (int i = t; i < nbk; i += 1024) { lcnt[i] = 0; lcnt2[i] = 0; }
  __syncthreads();
  int c0 = blockIdx.x * chunk;
  int c1 = min(E, c0 + chunk);
  for (int e = c0 + t; e < c1; e += 1024)
    atomicAdd(&lcnt[dst[e] >> NPB_SHIFT], 1);
  __syncthreads();
  for (int i = t; i < nbk; i += 1024) {
    int c = lcnt[i];
    lbase[i] = c ? (i * BCAP + atomicAdd(&bcur[i], c)) : 0;
  }
  __syncthreads();
  for (int e = c0 + t; e < c1; e += 1024) {
    int d = dst[e];
    int b = d >> NPB_SHIFT;
    int pos = lbase[b] + atomicAdd(&lcnt2[b], 1);
    tmp[pos] = make_int2(((d & (NPB - 1)) << 20) | src[e], __float_as_int(ea[e]));
  }
}

__global__ __launch_bounds__(256) void k_bucket_to_csr(
    const int2* __restrict__ tmp, const int* __restrict__ bcur,
    int N, int ET, int2* __restrict__ eidx, int* __restrict__ row_ptr) {
  __shared__ int cnt[NPB], sc[NPB], cur[NPB];
  __shared__ int wsum[4];
  int b = blockIdx.x;
  int n0 = b << NPB_SHIFT;
  int nn = min(NPB, N - n0);
  int t = threadIdx.x;
  int psum = 0;
  for (int i = t; i < b; i += 256) psum += bcur[i];
  #pragma unroll
  for (int off = 32; off; off >>= 1) psum += __shfl_xor(psum, off, 64);
  if ((t & 63) == 0) wsum[t >> 6] = psum;
  if (t < NPB) cnt[t] = 0;
  __syncthreads();
  int prefix = wsum[0] + wsum[1] + wsum[2] + wsum[3];
  int cb = bcur[b];
  int i0 = b * BCAP, i1 = i0 + cb;
  for (int i = i0 + t; i < i1; i += 256)
    atomicAdd(&cnt[(tmp[i].x >> 20) & (NPB - 1)], 1);
  __syncthreads();
  int v = (t < NPB) ? cnt[t] : 0;
  int x = v;
  if (t < NPB) sc[t] = x;
  __syncthreads();
  for (int off = 1; off < NPB; off <<= 1) {
    int y = (t >= off && t < NPB) ? sc[t - off] : 0;
    __syncthreads();
    if (t < NPB) { x += y; sc[t] = x; }
    __syncthreads();
  }
  int w0 = prefix + n0;
  if (t < nn) {
    int node = n0 + t;
    int base = w0 + (x - v) + t;
    row_ptr[node] = base;
    eidx[base] = make_int2(node, __float_as_int(1.0f));  // self loop first
    cur[t] = base + 1;
  }
  if (b == 0 && t == 0) row_ptr[N] = ET;
  __syncthreads();
  for (int i = i0 + t; i < i1; i += 256) {
    int2 r = tmp[i];
    int pos = atomicAdd(&cur[(r.x >> 20) & (NPB - 1)], 1);
    eidx[pos] = make_int2(r.x & 0xFFFFF, r.y);
  }
}

// ---------------- node linear via MFMA ----------------

template<int CIN, bool IN_HALF>
__global__ __launch_bounds__(256) void k_lin2_mfma(
    const void* __restrict__ hin,
    const float* __restrict__ Wl, const float* __restrict__ bl,
    const float* __restrict__ Wr, const float* __restrict__ br,
    _Float16* __restrict__ xlh, _Float16* __restrict__ xrh, int N) {
  constexpr int LDK = CIN + 8;               // +16B pad: 2-way banks only
  __shared__ _Float16 sA[64 * LDK];
  __shared__ _Float16 sBt[128 * LDK];        // W^T: [col][k]
  const int t = threadIdx.x;
  const int row0 = blockIdx.x * 64;

  {
    int c = t >> 1, half = t & 1;
    const float* Wsrc = (c < 64) ? Wl : Wr;
    int col = c & 63;
    int k0 = half * (CIN / 2);
    #pragma unroll 4
    for (int k = 0; k < CIN / 2; k += 2) {
      float w0 = Wsrc[(size_t)(k0 + k) * 64 + col];
      float w1 = Wsrc[(size_t)(k0 + k + 1) * 64 + col];
      F16U u; u.v = (f16x2){(_Float16)w0, (_Float16)w1};
      *(unsigned int*)&sBt[c * LDK + k0 + k] = u.u;
    }
  }
  #pragma unroll
  for (int i = 0; i < CIN / 16; i++) {
    int flat = i * 1024 + t * 4;
    int r = flat / CIN, k = flat & (CIN - 1);
    uint2 w;
    if constexpr (IN_HALF) {
      const _Float16* h = (const _Float16*)hin;
      w = (row0 + r < N) ? *(const uint2*)&h[(size_t)(row0 + r) * CIN + k]
                         : make_uint2(0, 0);
    } else {
      const float* h = (const float*)hin;
      float4 v = make_float4(0.f, 0.f, 0.f, 0.f);
      if (row0 + r < N) v = *(const float4*)&h[(size_t)(row0 + r) * CIN + k];
      F16U ua, ub;
      ua.v = (f16x2){(_Float16)v.x, (_Float16)v.y};
      ub.v = (f16x2){(_Float16)v.z, (_Float16)v.w};
      w = make_uint2(ua.u, ub.u);
    }
    *(uint2*)&sA[r * LDK + k] = w;
  }
  __syncthreads();

  const int wid = t >> 6, lane = t & 63;
  const int arow = (wid << 4) + (lane & 15);
  const int koff = (lane >> 4) << 2;

  float bv[8];
  #pragma unroll
  for (int ct = 0; ct < 8; ct++) {
    int c = ct * 16 + (lane & 15);
    bv[ct] = (c < 64) ? bl[c] : br[c & 63];
  }

  f32x4 acc[8];
  #pragma unroll
  for (int ct = 0; ct < 8; ct++) acc[ct] = (f32x4){0.f, 0.f, 0.f, 0.f};

  const _Float16* aBase = &sA[arow * LDK + koff];
  #pragma unroll
  for (int ks = 0; ks < CIN; ks += 16) {
    f16x4 a = *(const f16x4*)(aBase + ks);
    #pragma unroll
    for (int ct = 0; ct < 8; ct++) {
      f16x4 b = *(const f16x4*)&sBt[(ct * 16 + (lane & 15)) * LDK + koff + ks];
      acc[ct] = __builtin_amdgcn_mfma_f32_16x16x16f16(a, b, acc[ct], 0, 0, 0);
    }
  }

  const int rbase = row0 + (wid << 4) + ((lane >> 4) << 2);
  #pragma unroll
  for (int j = 0; j < 4; j++) {
    int row = rbase + j;
    if (row < N) {
      #pragma unroll
      for (int ct = 0; ct < 8; ct++) {
        int c = ct * 16 + (lane & 15);
        _Float16* o = (c < 64) ? xlh : xrh;
        o[(size_t)row * 64 + (c & 63)] = (_Float16)(acc[ct][j] + bv[ct]);
      }
    }
  }
}

// ---------------- per-dst-node edge pass ----------------
// 4 groups per wave (16 lanes x 4 channels), packed-fp16 math, deferred-max
// online segment softmax in exp2 units (att pre-scaled by log2e), 2-edge
// paired loop body (amortizes loop/branch/shift), A/B prefetch as in r9.

#define THR_L2 8.0f   // defer-rescale threshold in log2 units (weights <= 256)

template<bool OUT_HALF>
__global__ __launch_bounds__(256) void k_gat_edge(
    const _Float16* __restrict__ xlh, const _Float16* __restrict__ xrh,
    const int* __restrict__ row_ptr, const int2* __restrict__ eidx,
    const float* __restrict__ We, const float* __restrict__ att,
    const float* __restrict__ bias,
    void* __restrict__ outp, int N) {
  int n = (blockIdx.x * blockDim.x + threadIdx.x) >> 6;  // one wave per node
  if (n >= N) return;
  int lane = threadIdx.x & 63;
  int g = lane >> 4;
  int cb = (lane & 15) * 4;

  uint2 xiu = *(const uint2*)&xrh[(size_t)n * 64 + cb];
  F16U uxa, uxb; uxa.u = xiu.x; uxb.u = xiu.y;
  f16x2 xi01 = uxa.v, xi23 = uxb.v;
  float4 wef = *(const float4*)&We[cb];
  float4 atf = *(const float4*)&att[cb];
  const float L2E = 1.4426950408889634f;     // log2(e): p in log2 units
  f16x2 we01 = {(_Float16)wef.x, (_Float16)wef.y};
  f16x2 we23 = {(_Float16)wef.z, (_Float16)wef.w};
  f16x2 at01 = {(_Float16)(atf.x * L2E), (_Float16)(atf.y * L2E)};
  f16x2 at23 = {(_Float16)(atf.z * L2E), (_Float16)(atf.w * L2E)};
  const f16x2 zz  = {(_Float16)0.f, (_Float16)0.f};
  const f16x2 c02 = {(_Float16)0.2f, (_Float16)0.2f};

  int e0 = row_ptr[n], e1 = row_ptr[n + 1];

  float m = -INFINITY, s = 0.f;
  float4 acc = make_float4(0.f, 0.f, 0.f, 0.f);

  int e = e0 + g;
  int2 mA = make_int2(0, 0), mB = make_int2(0, 0);
  uint2 rA = make_uint2(0, 0), rB = make_uint2(0, 0);
  if (e < e1) {
    mA = eidx[e];
    rA = *(const uint2*)&xlh[(size_t)mA.x * 64 + cb];
  }
  if (e + 4 < e1) {
    mB = eidx[e + 4];
    rB = *(const uint2*)&xlh[(size_t)mB.x * 64 + cb];
  }

  // paired loop: edges e (slot A) and e+4 (slot B) both valid
  while (e + 4 < e1) {
    int2 cmA = mA, cmB = mB;
    uint2 crA = rA, crB = rB;
    if (e + 8 < e1) {   // prefetch next pair (same in-iteration dep as r9)
      mA = eidx[e + 8];
      rA = *(const uint2*)&xlh[(size_t)mA.x * 64 + cb];
    }
    if (e + 12 < e1) {
      mB = eidx[e + 12];
      rB = *(const uint2*)&xlh[(size_t)mB.x * 64 + cb];
    }
    // ---- edge A ----
    F16U uA0, uA1; uA0.u = crA.x; uA1.u = crA.y;
    f16x2 xjA01 = uA0.v, xjA23 = uA1.v;
    _Float16 eaA = (_Float16)__int_as_float(cmA.y);
    f16x2 eaA2 = {eaA, eaA};
    f16x2 zA01 = __builtin_elementwise_fma(eaA2, we01, xi01 + xjA01);
    f16x2 zA23 = __builtin_elementwise_fma(eaA2, we23, xi23 + xjA23);
    f16x2 lA01 = __builtin_elementwise_fma(
        c02, __builtin_elementwise_min(zA01, zz), __builtin_elementwise_max(zA01, zz));
    f16x2 lA23 = __builtin_elementwise_fma(
        c02, __builtin_elementwise_min(zA23, zz), __builtin_elementwise_max(zA23, zz));
    float p1 = __builtin_amdgcn_fdot2(lA01, at01,
               __builtin_amdgcn_fdot2(lA23, at23, 0.f, false), false);
    // ---- edge B ----
    F16U uB0, uB1; uB0.u = crB.x; uB1.u = crB.y;
    f16x2 xjB01 = uB0.v, xjB23 = uB1.v;
    _Float16 eaB = (_Float16)__int_as_float(cmB.y);
    f16x2 eaB2 = {eaB, eaB};
    f16x2 zB01 = __builtin_elementwise_fma(eaB2, we01, xi01 + xjB01);
    f16x2 zB23 = __builtin_elementwise_fma(eaB2, we23, xi23 + xjB23);
    f16x2 lB01 = __builtin_elementwise_fma(
        c02, __builtin_elementwise_min(zB01, zz), __builtin_elementwise_max(zB01, zz));
    f16x2 lB23 = __builtin_elementwise_fma(
        c02, __builtin_elementwise_min(zB23, zz), __builtin_elementwise_max(zB23, zz));
    float p2 = __builtin_amdgcn_fdot2(lB01, at01,
               __builtin_amdgcn_fdot2(lB23, at23, 0.f, false), false);
    // two independent 4-step reduces (dual-issue friendly)
    #pragma unroll
    for (int off = 1; off < 16; off <<= 1) {
      p1 += __shfl_xor(p1, off, 64);
      p2 += __shfl_xor(p2, off, 64);
    }
    // paired deferred-max update (one decision for both edges)
    float pm = fmaxf(p1, p2);
    if (pm > m + THR_L2) {
      float coef = exp2f(m - pm);          // 0 on first pair (m=-inf)
      float w1 = exp2f(p1 - pm);
      float w2 = exp2f(p2 - pm);
      s = fmaf(s, coef, w1 + w2);
      acc.x = fmaf(acc.x, coef, fmaf(w1, (float)xjA01[0], w2 * (float)xjB01[0]));
      acc.y = fmaf(acc.y, coef, fmaf(w1, (float)xjA01[1], w2 * (float)xjB01[1]));
      acc.z = fmaf(acc.z, coef, fmaf(w1, (float)xjA23[0], w2 * (float)xjB23[0]));
      acc.w = fmaf(acc.w, coef, fmaf(w1, (float)xjA23[1], w2 * (float)xjB23[1]));
      m = pm;
    } else {
      float w1 = exp2f(p1 - m);            // bounded by 2^THR_L2
      float w2 = exp2f(p2 - m);
      s += w1 + w2;
      acc.x += fmaf(w1, (float)xjA01[0], w2 * (float)xjB01[0]);
      acc.y += fmaf(w1, (float)xjA01[1], w2 * (float)xjB01[1]);
      acc.z += fmaf(w1, (float)xjA23[0], w2 * (float)xjB23[0]);
      acc.w += fmaf(w1, (float)xjA23[1], w2 * (float)xjB23[1]);
    }
    e += 8;
  }

  // tail: at most one edge left, in slot A
  if (e < e1) {
    F16U u0, u1; u0.u = rA.x; u1.u = rA.y;
    f16x2 xj01 = u0.v, xj23 = u1.v;
    _Float16 eah = (_Float16)__int_as_float(mA.y);
    f16x2 ea2 = {eah, eah};
    f16x2 z01 = __builtin_elementwise_fma(ea2, we01, xi01 + xj01);
    f16x2 z23 = __builtin_elementwise_fma(ea2, we23, xi23 + xj23);
    f16x2 l01 = __builtin_elementwise_fma(
        c02, __builtin_elementwise_min(z01, zz), __builtin_elementwise_max(z01, zz));
    f16x2 l23 = __builtin_elementwise_fma(
        c02, __builtin_elementwise_min(z23, zz), __builtin_elementwise_max(z23, zz));
    float p = __builtin_amdgcn_fdot2(l01, at01,
              __builtin_amdgcn_fdot2(l23, at23, 0.f, false), false);
    #pragma unroll
    for (int off = 1; off < 16; off <<= 1) p += __shfl_xor(p, off, 64);
    if (p > m + THR_L2) {
      float coef = exp2f(m - p);
      s = fmaf(s, coef, 1.f);
      acc.x = fmaf(acc.x, coef, (float)xj01[0]);
      acc.y = fmaf(acc.y, coef, (float)xj01[1]);
      acc.z = fmaf(acc.z, coef, (float)xj23[0]);
      acc.w = fmaf(acc.w, coef, (float)xj23[1]);
      m = p;
    } else {
      float wgt = exp2f(p - m);
      s += wgt;
      acc.x = fmaf(wgt, (float)xj01[0], acc.x);
      acc.y = fmaf(wgt, (float)xj01[1], acc.y);
      acc.z = fmaf(wgt, (float)xj23[0], acc.z);
      acc.w = fmaf(wgt, (float)xj23[1], acc.w);
    }
  }

  // merge the 4 group states (lane^16/32 hold same channels)
  #pragma unroll
  for (int off = 16; off <= 32; off <<= 1) {
    float mo = __shfl_xor(m, off, 64);
    float so = __shfl_xor(s, off, 64);
    float4 ao;
    ao.x = __shfl_xor(acc.x, off, 64);
    ao.y = __shfl_xor(acc.y, off, 64);
    ao.z = __shfl_xor(acc.z, off, 64);
    ao.w = __shfl_xor(acc.w, off, 64);
    float mn = fmaxf(m, mo);
    float cs = (m == -INFINITY) ? 0.f : exp2f(m - mn);
    float co = (mo == -INFINITY) ? 0.f : exp2f(mo - mn);
    s = s * cs + so * co;
    acc.x = acc.x * cs + ao.x * co;
    acc.y = acc.y * cs + ao.y * co;
    acc.z = acc.z * cs + ao.z * co;
    acc.w = acc.w * cs + ao.w * co;
    m = mn;
  }

  if (g == 0) {
    float inv = 1.0f / s;
    float o0 = acc.x * inv + bias[cb + 0];
    float o1 = acc.y * inv + bias[cb + 1];
    float o2 = acc.z * inv + bias[cb + 2];
    float o3 = acc.w * inv + bias[cb + 3];
    if constexpr (OUT_HALF) {
      F16U ua, ub;
      ua.v = (f16x2){(_Float16)o0, (_Float16)o1};
      ub.v = (f16x2){(_Float16)o2, (_Float16)o3};
      *(uint2*)&((_Float16*)outp)[(size_t)n * 64 + cb] = make_uint2(ua.u, ub.u);
    } else {
      *(float4*)&((float*)outp)[(size_t)n * 64 + cb] = make_float4(o0, o1, o2, o3);
    }
  }
}

// ---------------- launch ----------------

extern "C" void kernel_launch(void* const* d_in, const int* in_sizes, int n_in,
                              void* d_out, int out_size, void* d_ws, size_t ws_size,
                              hipStream_t stream) {
  const float* x    = (const float*)d_in[0];
  const int*   ei   = (const int*)d_in[1];
  const float* ea   = (const float*)d_in[2];
  const float* Wl0  = (const float*)d_in[3];
  const float* bl0  = (const float*)d_in[4];
  const float* Wr0  = (const float*)d_in[5];
  const float* br0  = (const float*)d_in[6];
  const float* We0  = (const float*)d_in[7];
  const float* att0 = (const float*)d_in[8];
  const float* bias0= (const float*)d_in[9];
  const float* Wl1  = (const float*)d_in[10];
  const float* bl1  = (const float*)d_in[11];
  const float* Wr1  = (const float*)d_in[12];
  const float* br1  = (const float*)d_in[13];
  const float* We1  = (const float*)d_in[14];
  const float* att1 = (const float*)d_in[15];
  const float* bias1= (const float*)d_in[16];

  const int N  = in_sizes[0] / 128;
  const int E  = in_sizes[1] / 2;
  const int ET = E + N;
  const int* src = ei;
  const int* dst = ei + E;
  const int nbk = (N + NPB - 1) >> NPB_SHIFT;

  char* w = (char*)d_ws;
  _Float16* xlh  = (_Float16*)w; w += (size_t)N * 64 * 2;  // fp16 gather table (src side)
  _Float16* xrh  = (_Float16*)w; w += (size_t)N * 64 * 2;  // fp16 table (dst side)
  _Float16* h1h  = (_Float16*)w; w += (size_t)N * 64 * 2;  // fp16 layer-0 output
  int*    row_ptr= (int*)w;    w += (size_t)(N + 2) * 4;
  int2*   eidx   = (int2*)w;   w += (size_t)ET * 8;
  int*    bcur   = (int*)w;    w += NBK_MAX * 4;
  // tmp aliases xlh+xrh (N*256 B = 12.8 MB >= nbk*BCAP*8 = 11.2 MB):
  // CSR build completes before layer-0 lin2 writes the tables.
  int2*   tmp    = (int2*)xlh;

  float* out = (float*)d_out;

  // ---- CSR build (fixed-cap buckets; same graph for both layers) ----
  {
    int nblk = 256;
    int chunk = (E + nblk - 1) / nblk;
    (void)hipMemsetAsync(bcur, 0, (size_t)nbk * 4, stream);
    k_scatter_agg<<<nblk, 1024, 0, stream>>>(src, dst, ea, E, nbk, chunk, bcur, tmp);
    k_bucket_to_csr<<<nbk, 256, 0, stream>>>(tmp, bcur, N, ET, eidx, row_ptr);
  }

  int nblk = (N + 63) / 64;
  // ---- layer 0: 128 -> 64 ----
  k_lin2_mfma<128, false><<<nblk, 256, 0, stream>>>(x, Wl0, bl0, Wr0, br0, xlh, xrh, N);
  k_gat_edge<true><<<(N + 3) / 4, 256, 0, stream>>>(xlh, xrh, row_ptr, eidx, We0, att0, bias0, h1h, N);
  // ---- layer 1: 64 -> 64 ----
  k_lin2_mfma<64, true><<<nblk, 256, 0, stream>>>(h1h, Wl1, bl1, Wr1, br1, xlh, xrh, N);
  k_gat_edge<false><<<(N + 3) / 4, 256, 0, stream>>>(xlh, xrh, row_ptr, eidx, We1, att1, bias1, out, N);
}

// Round 16
// 157.025 us; speedup vs baseline: 1.0383x; 1.0383x over previous
//
#include <hip/hip_runtime.h>
#include <math.h>

// nodes-per-bucket = 128 (pow2). nbk = ceil(N/128) buckets (<= 512 for N<=65536).
#define NPB_SHIFT 7
#define NPB 128
#define NBK_MAX 512
#define BCAP 3584   // fixed bucket capacity; Poisson(2688) edges/bucket, 17 sigma

typedef _Float16 f16x2 __attribute__((ext_vector_type(2)));
typedef _Float16 f16x4 __attribute__((ext_vector_type(4)));
typedef float f32x4 __attribute__((ext_vector_type(4)));
union F16U { f16x2 v; unsigned int u; };

// ---------------- CSR build (fixed-capacity buckets) ----------

__global__ __launch_bounds__(1024) void k_scatter_agg(
    const int* __restrict__ src, const int* __restrict__ dst,
    const float* __restrict__ ea, int E, int nbk, int chunk,
    int* bcur, int2* __restrict__ tmp) {
  __shared__ int lcnt[NBK_MAX], lcnt2[NBK_MAX], lbase[NBK_MAX];
  int t = threadIdx.x;
  for (int i = t; i < nbk; i += 1024) { lcnt[i] = 0; lcnt2[i] = 0; }
  __syncthreads();
  int c0 = blockIdx.x * chunk;
  int c1 = min(E, c0 + chunk);
  for (int e = c0 + t; e < c1; e += 1024)
    atomicAdd(&lcnt[dst[e] >> NPB_SHIFT], 1);
  __syncthreads();
  for (int i = t; i < nbk; i += 1024) {
    int c = lcnt[i];
    lbase[i] = c ? (i * BCAP + atomicAdd(&bcur[i], c)) : 0;
  }
  __syncthreads();
  for (int e = c0 + t; e < c1; e += 1024) {
    int d = dst[e];
    int b = d >> NPB_SHIFT;
    int pos = lbase[b] + atomicAdd(&lcnt2[b], 1);
    tmp[pos] = make_int2(((d & (NPB - 1)) << 20) | src[e], __float_as_int(ea[e]));
  }
}

__global__ __launch_bounds__(256) void k_bucket_to_csr(
    const int2* __restrict__ tmp, const int* __restrict__ bcur,
    int N, int ET, int2* __restrict__ eidx, int* __restrict__ row_ptr) {
  __shared__ int cnt[NPB], sc[NPB], cur[NPB];
  __shared__ int wsum[4];
  int b = blockIdx.x;
  int n0 = b << NPB_SHIFT;
  int nn = min(NPB, N - n0);
  int t = threadIdx.x;
  int psum = 0;
  for (int i = t; i < b; i += 256) psum += bcur[i];
  #pragma unroll
  for (int off = 32; off; off >>= 1) psum += __shfl_xor(psum, off, 64);
  if ((t & 63) == 0) wsum[t >> 6] = psum;
  if (t < NPB) cnt[t] = 0;
  __syncthreads();
  int prefix = wsum[0] + wsum[1] + wsum[2] + wsum[3];
  int cb = bcur[b];
  int i0 = b * BCAP, i1 = i0 + cb;
  for (int i = i0 + t; i < i1; i += 256)
    atomicAdd(&cnt[(tmp[i].x >> 20) & (NPB - 1)], 1);
  __syncthreads();
  int v = (t < NPB) ? cnt[t] : 0;
  int x = v;
  if (t < NPB) sc[t] = x;
  __syncthreads();
  for (int off = 1; off < NPB; off <<= 1) {
    int y = (t >= off && t < NPB) ? sc[t - off] : 0;
    __syncthreads();
    if (t < NPB) { x += y; sc[t] = x; }
    __syncthreads();
  }
  int w0 = prefix + n0;
  if (t < nn) {
    int node = n0 + t;
    int base = w0 + (x - v) + t;
    row_ptr[node] = base;
    eidx[base] = make_int2(node, __float_as_int(1.0f));  // self loop first
    cur[t] = base + 1;
  }
  if (b == 0 && t == 0) row_ptr[N] = ET;
  __syncthreads();
  for (int i = i0 + t; i < i1; i += 256) {
    int2 r = tmp[i];
    int pos = atomicAdd(&cur[(r.x >> 20) & (NPB - 1)], 1);
    eidx[pos] = make_int2(r.x & 0xFFFFF, r.y);
  }
}

// ---------------- node linear via MFMA ----------------
// [xl|xr] = h @ [Wl|Wr] + [bl|br], fp16 in (staged), f32 accum, fp16 out.
// Block: 256 thr = 4 waves; tile 64 rows x 128 cols; full CIN resident in LDS.
// mfma_f32_16x16x16f16 classic layout: A[l&15][(l>>4)*4+j],
// B[(l>>4)*4+j][l&15], D row=(l>>4)*4+reg, col=l&15.

template<int CIN, bool IN_HALF>
__global__ __launch_bounds__(256) void k_lin2_mfma(
    const void* __restrict__ hin,
    const float* __restrict__ Wl, const float* __restrict__ bl,
    const float* __restrict__ Wr, const float* __restrict__ br,
    _Float16* __restrict__ xlh, _Float16* __restrict__ xrh, int N) {
  constexpr int LDK = CIN + 8;               // +16B pad: 2-way banks only
  __shared__ _Float16 sA[64 * LDK];
  __shared__ _Float16 sBt[128 * LDK];        // W^T: [col][k]
  const int t = threadIdx.x;
  const int row0 = blockIdx.x * 64;

  // ---- stage W^T (tiny, L2-hot after first blocks) ----
  {
    int c = t >> 1, half = t & 1;
    const float* Wsrc = (c < 64) ? Wl : Wr;
    int col = c & 63;
    int k0 = half * (CIN / 2);
    #pragma unroll 4
    for (int k = 0; k < CIN / 2; k += 2) {
      float w0 = Wsrc[(size_t)(k0 + k) * 64 + col];
      float w1 = Wsrc[(size_t)(k0 + k + 1) * 64 + col];
      F16U u; u.v = (f16x2){(_Float16)w0, (_Float16)w1};
      *(unsigned int*)&sBt[c * LDK + k0 + k] = u.u;
    }
  }
  // ---- stage A tile (64 x CIN) ----
  #pragma unroll
  for (int i = 0; i < CIN / 16; i++) {
    int flat = i * 1024 + t * 4;             // element index
    int r = flat / CIN, k = flat & (CIN - 1);
    uint2 w;
    if constexpr (IN_HALF) {
      const _Float16* h = (const _Float16*)hin;
      w = (row0 + r < N) ? *(const uint2*)&h[(size_t)(row0 + r) * CIN + k]
                         : make_uint2(0, 0);
    } else {
      const float* h = (const float*)hin;
      float4 v = make_float4(0.f, 0.f, 0.f, 0.f);
      if (row0 + r < N) v = *(const float4*)&h[(size_t)(row0 + r) * CIN + k];
      F16U ua, ub;
      ua.v = (f16x2){(_Float16)v.x, (_Float16)v.y};
      ub.v = (f16x2){(_Float16)v.z, (_Float16)v.w};
      w = make_uint2(ua.u, ub.u);
    }
    *(uint2*)&sA[r * LDK + k] = w;
  }
  __syncthreads();

  const int wid = t >> 6, lane = t & 63;
  const int arow = (wid << 4) + (lane & 15);
  const int koff = (lane >> 4) << 2;

  float bv[8];
  #pragma unroll
  for (int ct = 0; ct < 8; ct++) {
    int c = ct * 16 + (lane & 15);
    bv[ct] = (c < 64) ? bl[c] : br[c & 63];
  }

  f32x4 acc[8];
  #pragma unroll
  for (int ct = 0; ct < 8; ct++) acc[ct] = (f32x4){0.f, 0.f, 0.f, 0.f};

  const _Float16* aBase = &sA[arow * LDK + koff];
  #pragma unroll
  for (int ks = 0; ks < CIN; ks += 16) {
    f16x4 a = *(const f16x4*)(aBase + ks);
    #pragma unroll
    for (int ct = 0; ct < 8; ct++) {
      f16x4 b = *(const f16x4*)&sBt[(ct * 16 + (lane & 15)) * LDK + koff + ks];
      acc[ct] = __builtin_amdgcn_mfma_f32_16x16x16f16(a, b, acc[ct], 0, 0, 0);
    }
  }

  const int rbase = row0 + (wid << 4) + ((lane >> 4) << 2);
  #pragma unroll
  for (int j = 0; j < 4; j++) {
    int row = rbase + j;
    if (row < N) {
      #pragma unroll
      for (int ct = 0; ct < 8; ct++) {
        int c = ct * 16 + (lane & 15);
        _Float16* o = (c < 64) ? xlh : xrh;
        o[(size_t)row * 64 + (c & 63)] = (_Float16)(acc[ct][j] + bv[ct]);
      }
    }
  }
}

// ---------------- per-dst-node edge pass (r9 structure: best measured) ------
// 4 groups per wave (16 lanes x 4 channels), packed-fp16 math, deferred-max
// online segment softmax, 2-deep A/B prefetch. OUT_HALF: layer-0 writes fp16.

#define RESCALE_THR 8.0f

template<bool OUT_HALF>
__global__ __launch_bounds__(256) void k_gat_edge(
    const _Float16* __restrict__ xlh, const _Float16* __restrict__ xrh,
    const int* __restrict__ row_ptr, const int2* __restrict__ eidx,
    const float* __restrict__ We, const float* __restrict__ att,
    const float* __restrict__ bias,
    void* __restrict__ outp, int N) {
  int n = (blockIdx.x * blockDim.x + threadIdx.x) >> 6;  // one wave per node
  if (n >= N) return;
  int lane = threadIdx.x & 63;
  int g = lane >> 4;
  int cb = (lane & 15) * 4;

  uint2 xiu = *(const uint2*)&xrh[(size_t)n * 64 + cb];
  F16U uxa, uxb; uxa.u = xiu.x; uxb.u = xiu.y;
  f16x2 xi01 = uxa.v, xi23 = uxb.v;
  float4 wef = *(const float4*)&We[cb];
  float4 atf = *(const float4*)&att[cb];
  f16x2 we01 = {(_Float16)wef.x, (_Float16)wef.y};
  f16x2 we23 = {(_Float16)wef.z, (_Float16)wef.w};
  f16x2 at01 = {(_Float16)atf.x, (_Float16)atf.y};
  f16x2 at23 = {(_Float16)atf.z, (_Float16)atf.w};
  const f16x2 zz  = {(_Float16)0.f, (_Float16)0.f};
  const f16x2 c02 = {(_Float16)0.2f, (_Float16)0.2f};

  int e0 = row_ptr[n], e1 = row_ptr[n + 1];

  float m = -INFINITY, s = 0.f;
  float4 acc = make_float4(0.f, 0.f, 0.f, 0.f);

  int e = e0 + g;
  int2 metaA = make_int2(0, 0), metaB = make_int2(0, 0);
  uint2 rawA = make_uint2(0, 0), rawB = make_uint2(0, 0);
  if (e < e1) {
    metaA = eidx[e];
    rawA = *(const uint2*)&xlh[(size_t)metaA.x * 64 + cb];
  }
  if (e + 4 < e1) {
    metaB = eidx[e + 4];
    rawB = *(const uint2*)&xlh[(size_t)metaB.x * 64 + cb];
  }

  while (e < e1) {
    int2 cm = metaA;
    uint2 craw = rawA;
    metaA = metaB;
    rawA = rawB;
    int en2 = e + 8;
    if (en2 < e1) {  // prefetch 2 iterations ahead
      metaB = eidx[en2];
      rawB = *(const uint2*)&xlh[(size_t)metaB.x * 64 + cb];
    }
    F16U u0, u1; u0.u = craw.x; u1.u = craw.y;
    f16x2 xj01 = u0.v, xj23 = u1.v;
    float eav = __int_as_float(cm.y);
    _Float16 eah = (_Float16)eav;
    f16x2 ea2 = {eah, eah};
    f16x2 z01 = __builtin_elementwise_fma(ea2, we01, xi01 + xj01);
    f16x2 z23 = __builtin_elementwise_fma(ea2, we23, xi23 + xj23);
    f16x2 l01 = __builtin_elementwise_fma(
        c02, __builtin_elementwise_min(z01, zz), __builtin_elementwise_max(z01, zz));
    f16x2 l23 = __builtin_elementwise_fma(
        c02, __builtin_elementwise_min(z23, zz), __builtin_elementwise_max(z23, zz));
    float p = __builtin_amdgcn_fdot2(l01, at01,
              __builtin_amdgcn_fdot2(l23, at23, 0.f, false), false);
    #pragma unroll
    for (int off = 1; off < 16; off <<= 1) p += __shfl_xor(p, off, 64);
    if (p > m + RESCALE_THR) {
      float coef = __expf(m - p);
      s = fmaf(s, coef, 1.f);
      acc.x = fmaf(acc.x, coef, (float)xj01[0]);
      acc.y = fmaf(acc.y, coef, (float)xj01[1]);
      acc.z = fmaf(acc.z, coef, (float)xj23[0]);
      acc.w = fmaf(acc.w, coef, (float)xj23[1]);
      m = p;
    } else {
      float wgt = __expf(p - m);
      s += wgt;
      acc.x = fmaf(wgt, (float)xj01[0], acc.x);
      acc.y = fmaf(wgt, (float)xj01[1], acc.y);
      acc.z = fmaf(wgt, (float)xj23[0], acc.z);
      acc.w = fmaf(wgt, (float)xj23[1], acc.w);
    }
    e += 4;
  }

  #pragma unroll
  for (int off = 16; off <= 32; off <<= 1) {
    float mo = __shfl_xor(m, off, 64);
    float so = __shfl_xor(s, off, 64);
    float4 ao;
    ao.x = __shfl_xor(acc.x, off, 64);
    ao.y = __shfl_xor(acc.y, off, 64);
    ao.z = __shfl_xor(acc.z, off, 64);
    ao.w = __shfl_xor(acc.w, off, 64);
    float mn = fmaxf(m, mo);
    float cs = (m == -INFINITY) ? 0.f : __expf(m - mn);
    float co = (mo == -INFINITY) ? 0.f : __expf(mo - mn);
    s = s * cs + so * co;
    acc.x = acc.x * cs + ao.x * co;
    acc.y = acc.y * cs + ao.y * co;
    acc.z = acc.z * cs + ao.z * co;
    acc.w = acc.w * cs + ao.w * co;
    m = mn;
  }

  if (g == 0) {
    float inv = 1.0f / s;
    float o0 = acc.x * inv + bias[cb + 0];
    float o1 = acc.y * inv + bias[cb + 1];
    float o2 = acc.z * inv + bias[cb + 2];
    float o3 = acc.w * inv + bias[cb + 3];
    if constexpr (OUT_HALF) {
      F16U ua, ub;
      ua.v = (f16x2){(_Float16)o0, (_Float16)o1};
      ub.v = (f16x2){(_Float16)o2, (_Float16)o3};
      *(uint2*)&((_Float16*)outp)[(size_t)n * 64 + cb] = make_uint2(ua.u, ub.u);
    } else {
      *(float4*)&((float*)outp)[(size_t)n * 64 + cb] = make_float4(o0, o1, o2, o3);
    }
  }
}

// ---------------- launch ----------------

extern "C" void kernel_launch(void* const* d_in, const int* in_sizes, int n_in,
                              void* d_out, int out_size, void* d_ws, size_t ws_size,
                              hipStream_t stream) {
  const float* x    = (const float*)d_in[0];
  const int*   ei   = (const int*)d_in[1];
  const float* ea   = (const float*)d_in[2];
  const float* Wl0  = (const float*)d_in[3];
  const float* bl0  = (const float*)d_in[4];
  const float* Wr0  = (const float*)d_in[5];
  const float* br0  = (const float*)d_in[6];
  const float* We0  = (const float*)d_in[7];
  const float* att0 = (const float*)d_in[8];
  const float* bias0= (const float*)d_in[9];
  const float* Wl1  = (const float*)d_in[10];
  const float* bl1  = (const float*)d_in[11];
  const float* Wr1  = (const float*)d_in[12];
  const float* br1  = (const float*)d_in[13];
  const float* We1  = (const float*)d_in[14];
  const float* att1 = (const float*)d_in[15];
  const float* bias1= (const float*)d_in[16];

  const int N  = in_sizes[0] / 128;
  const int E  = in_sizes[1] / 2;
  const int ET = E + N;
  const int* src = ei;
  const int* dst = ei + E;
  const int nbk = (N + NPB - 1) >> NPB_SHIFT;

  char* w = (char*)d_ws;
  _Float16* xlh  = (_Float16*)w; w += (size_t)N * 64 * 2;  // fp16 gather table (src side)
  _Float16* xrh  = (_Float16*)w; w += (size_t)N * 64 * 2;  // fp16 table (dst side)
  _Float16* h1h  = (_Float16*)w; w += (size_t)N * 64 * 2;  // fp16 layer-0 output
  int*    row_ptr= (int*)w;    w += (size_t)(N + 2) * 4;
  int2*   eidx   = (int2*)w;   w += (size_t)ET * 8;
  int*    bcur   = (int*)w;    w += NBK_MAX * 4;
  // tmp aliases xlh+xrh (N*256 B = 12.8 MB >= nbk*BCAP*8 = 11.2 MB):
  // CSR build completes before layer-0 lin2 writes the tables.
  int2*   tmp    = (int2*)xlh;

  float* out = (float*)d_out;

  // ---- CSR build (fixed-cap buckets; same graph for both layers) ----
  {
    int nblk = 256;
    int chunk = (E + nblk - 1) / nblk;
    (void)hipMemsetAsync(bcur, 0, (size_t)nbk * 4, stream);
    k_scatter_agg<<<nblk, 1024, 0, stream>>>(src, dst, ea, E, nbk, chunk, bcur, tmp);
    k_bucket_to_csr<<<nbk, 256, 0, stream>>>(tmp, bcur, N, ET, eidx, row_ptr);
  }

  int nblk = (N + 63) / 64;
  // ---- layer 0: 128 -> 64 ----
  k_lin2_mfma<128, false><<<nblk, 256, 0, stream>>>(x, Wl0, bl0, Wr0, br0, xlh, xrh, N);
  k_gat_edge<true><<<(N + 3) / 4, 256, 0, stream>>>(xlh, xrh, row_ptr, eidx, We0, att0, bias0, h1h, N);
  // ---- layer 1: 64 -> 64 ----
  k_lin2_mfma<64, true><<<nblk, 256, 0, stream>>>(h1h, Wl1, bl1, Wr1, br1, xlh, xrh, N);
  k_gat_edge<false><<<(N + 3) / 4, 256, 0, stream>>>(xlh, xrh, row_ptr, eidx, We1, att1, bias1, out, N);
}

// Round 17
// 151.593 us; speedup vs baseline: 1.0755x; 1.0358x over previous
//
#include <hip/hip_runtime.h>
#include <math.h>

// nodes-per-bucket = 128 (pow2). nbk = ceil(N/128) buckets (<= 512 for N<=65536).
#define NPB_SHIFT 7
#define NPB 128
#define NBK_MAX 512
#define BCAP 3584   // fixed bucket capacity; Poisson(2688) edges/bucket, 17 sigma

typedef _Float16 f16x2 __attribute__((ext_vector_type(2)));
typedef _Float16 f16x4 __attribute__((ext_vector_type(4)));
typedef float f32x4 __attribute__((ext_vector_type(4)));
union F16U { f16x2 v; unsigned int u; };

// ---------------- CSR build (fixed-capacity buckets) ----------

__global__ __launch_bounds__(1024) void k_scatter_agg(
    const int* __restrict__ src, const int* __restrict__ dst,
    const float* __restrict__ ea, int E, int nbk, int chunk,
    int* bcur, int2* __restrict__ tmp) {
  __shared__ int lcnt[NBK_MAX], lcnt2[NBK_MAX], lbase[NBK_MAX];
  int t = threadIdx.x;
  for (int i = t; i < nbk; i += 1024) { lcnt[i] = 0; lcnt2[i] = 0; }
  __syncthreads();
  int c0 = blockIdx.x * chunk;
  int c1 = min(E, c0 + chunk);
  for (int e = c0 + t; e < c1; e += 1024)
    atomicAdd(&lcnt[dst[e] >> NPB_SHIFT], 1);
  __syncthreads();
  for (int i = t; i < nbk; i += 1024) {
    int c = lcnt[i];
    lbase[i] = c ? (i * BCAP + atomicAdd(&bcur[i], c)) : 0;
  }
  __syncthreads();
  for (int e = c0 + t; e < c1; e += 1024) {
    int d = dst[e];
    int b = d >> NPB_SHIFT;
    int pos = lbase[b] + atomicAdd(&lcnt2[b], 1);
    tmp[pos] = make_int2(((d & (NPB - 1)) << 20) | src[e], __float_as_int(ea[e]));
  }
}

__global__ __launch_bounds__(256) void k_bucket_to_csr(
    const int2* __restrict__ tmp, const int* __restrict__ bcur,
    int N, int ET, int2* __restrict__ eidx, int* __restrict__ row_ptr) {
  __shared__ int cnt[NPB], sc[NPB], cur[NPB];
  __shared__ int wsum[4];
  int b = blockIdx.x;
  int n0 = b << NPB_SHIFT;
  int nn = min(NPB, N - n0);
  int t = threadIdx.x;
  int psum = 0;
  for (int i = t; i < b; i += 256) psum += bcur[i];
  #pragma unroll
  for (int off = 32; off; off >>= 1) psum += __shfl_xor(psum, off, 64);
  if ((t & 63) == 0) wsum[t >> 6] = psum;
  if (t < NPB) cnt[t] = 0;
  __syncthreads();
  int prefix = wsum[0] + wsum[1] + wsum[2] + wsum[3];
  int cb = bcur[b];
  int i0 = b * BCAP, i1 = i0 + cb;
  for (int i = i0 + t; i < i1; i += 256)
    atomicAdd(&cnt[(tmp[i].x >> 20) & (NPB - 1)], 1);
  __syncthreads();
  int v = (t < NPB) ? cnt[t] : 0;
  int x = v;
  if (t < NPB) sc[t] = x;
  __syncthreads();
  for (int off = 1; off < NPB; off <<= 1) {
    int y = (t >= off && t < NPB) ? sc[t - off] : 0;
    __syncthreads();
    if (t < NPB) { x += y; sc[t] = x; }
    __syncthreads();
  }
  int w0 = prefix + n0;
  if (t < nn) {
    int node = n0 + t;
    int base = w0 + (x - v) + t;
    row_ptr[node] = base;
    eidx[base] = make_int2(node, __float_as_int(1.0f));  // self loop first
    cur[t] = base + 1;
  }
  if (b == 0 && t == 0) row_ptr[N] = ET;
  __syncthreads();
  for (int i = i0 + t; i < i1; i += 256) {
    int2 r = tmp[i];
    int pos = atomicAdd(&cur[(r.x >> 20) & (NPB - 1)], 1);
    eidx[pos] = make_int2(r.x & 0xFFFFF, r.y);
  }
}

// ---------------- node linear via MFMA ----------------
// [xl|xr] = h @ [Wl|Wr] + [bl|br], fp16 in (staged), f32 accum, fp16 out.
// Block: 256 thr = 4 waves; tile 64 rows x 128 cols; full CIN resident in LDS.
// mfma_f32_16x16x16f16 classic layout: A[l&15][(l>>4)*4+j],
// B[(l>>4)*4+j][l&15], D row=(l>>4)*4+reg, col=l&15.

template<int CIN, bool IN_HALF>
__global__ __launch_bounds__(256) void k_lin2_mfma(
    const void* __restrict__ hin,
    const float* __restrict__ Wl, const float* __restrict__ bl,
    const float* __restrict__ Wr, const float* __restrict__ br,
    _Float16* __restrict__ xlh, _Float16* __restrict__ xrh, int N) {
  constexpr int LDK = CIN + 8;               // +16B pad: 2-way banks only
  __shared__ _Float16 sA[64 * LDK];
  __shared__ _Float16 sBt[128 * LDK];        // W^T: [col][k]
  const int t = threadIdx.x;
  const int row0 = blockIdx.x * 64;

  // ---- stage W^T (tiny, L2-hot after first blocks) ----
  {
    int c = t >> 1, half = t & 1;
    const float* Wsrc = (c < 64) ? Wl : Wr;
    int col = c & 63;
    int k0 = half * (CIN / 2);
    #pragma unroll 4
    for (int k = 0; k < CIN / 2; k += 2) {
      float w0 = Wsrc[(size_t)(k0 + k) * 64 + col];
      float w1 = Wsrc[(size_t)(k0 + k + 1) * 64 + col];
      F16U u; u.v = (f16x2){(_Float16)w0, (_Float16)w1};
      *(unsigned int*)&sBt[c * LDK + k0 + k] = u.u;
    }
  }
  // ---- stage A tile (64 x CIN) ----
  #pragma unroll
  for (int i = 0; i < CIN / 16; i++) {
    int flat = i * 1024 + t * 4;             // element index
    int r = flat / CIN, k = flat & (CIN - 1);
    uint2 w;
    if constexpr (IN_HALF) {
      const _Float16* h = (const _Float16*)hin;
      w = (row0 + r < N) ? *(const uint2*)&h[(size_t)(row0 + r) * CIN + k]
                         : make_uint2(0, 0);
    } else {
      const float* h = (const float*)hin;
      float4 v = make_float4(0.f, 0.f, 0.f, 0.f);
      if (row0 + r < N) v = *(const float4*)&h[(size_t)(row0 + r) * CIN + k];
      F16U ua, ub;
      ua.v = (f16x2){(_Float16)v.x, (_Float16)v.y};
      ub.v = (f16x2){(_Float16)v.z, (_Float16)v.w};
      w = make_uint2(ua.u, ub.u);
    }
    *(uint2*)&sA[r * LDK + k] = w;
  }
  __syncthreads();

  const int wid = t >> 6, lane = t & 63;
  const int arow = (wid << 4) + (lane & 15);
  const int koff = (lane >> 4) << 2;

  float bv[8];
  #pragma unroll
  for (int ct = 0; ct < 8; ct++) {
    int c = ct * 16 + (lane & 15);
    bv[ct] = (c < 64) ? bl[c] : br[c & 63];
  }

  f32x4 acc[8];
  #pragma unroll
  for (int ct = 0; ct < 8; ct++) acc[ct] = (f32x4){0.f, 0.f, 0.f, 0.f};

  const _Float16* aBase = &sA[arow * LDK + koff];
  #pragma unroll
  for (int ks = 0; ks < CIN; ks += 16) {
    f16x4 a = *(const f16x4*)(aBase + ks);
    #pragma unroll
    for (int ct = 0; ct < 8; ct++) {
      f16x4 b = *(const f16x4*)&sBt[(ct * 16 + (lane & 15)) * LDK + koff + ks];
      acc[ct] = __builtin_amdgcn_mfma_f32_16x16x16f16(a, b, acc[ct], 0, 0, 0);
    }
  }

  const int rbase = row0 + (wid << 4) + ((lane >> 4) << 2);
  #pragma unroll
  for (int j = 0; j < 4; j++) {
    int row = rbase + j;
    if (row < N) {
      #pragma unroll
      for (int ct = 0; ct < 8; ct++) {
        int c = ct * 16 + (lane & 15);
        _Float16* o = (c < 64) ? xlh : xrh;
        o[(size_t)row * 64 + (c & 63)] = (_Float16)(acc[ct][j] + bv[ct]);
      }
    }
  }
}

// ---------------- per-dst-node edge pass (r9 structure; 1 wave per block) ---
// 4 groups per wave (16 lanes x 4 channels), packed-fp16 math, deferred-max
// online segment softmax, 2-deep A/B prefetch. OUT_HALF: layer-0 writes fp16.
// 64-thread blocks: one node per block -> no intra-block tail imbalance.

#define RESCALE_THR 8.0f

template<bool OUT_HALF>
__global__ __launch_bounds__(64) void k_gat_edge(
    const _Float16* __restrict__ xlh, const _Float16* __restrict__ xrh,
    const int* __restrict__ row_ptr, const int2* __restrict__ eidx,
    const float* __restrict__ We, const float* __restrict__ att,
    const float* __restrict__ bias,
    void* __restrict__ outp, int N) {
  int n = blockIdx.x;                         // one wave = one block = one node
  if (n >= N) return;
  int lane = threadIdx.x & 63;
  int g = lane >> 4;
  int cb = (lane & 15) * 4;

  uint2 xiu = *(const uint2*)&xrh[(size_t)n * 64 + cb];
  F16U uxa, uxb; uxa.u = xiu.x; uxb.u = xiu.y;
  f16x2 xi01 = uxa.v, xi23 = uxb.v;
  float4 wef = *(const float4*)&We[cb];
  float4 atf = *(const float4*)&att[cb];
  f16x2 we01 = {(_Float16)wef.x, (_Float16)wef.y};
  f16x2 we23 = {(_Float16)wef.z, (_Float16)wef.w};
  f16x2 at01 = {(_Float16)atf.x, (_Float16)atf.y};
  f16x2 at23 = {(_Float16)atf.z, (_Float16)atf.w};
  const f16x2 zz  = {(_Float16)0.f, (_Float16)0.f};
  const f16x2 c02 = {(_Float16)0.2f, (_Float16)0.2f};

  int e0 = row_ptr[n], e1 = row_ptr[n + 1];

  float m = -INFINITY, s = 0.f;
  float4 acc = make_float4(0.f, 0.f, 0.f, 0.f);

  int e = e0 + g;
  int2 metaA = make_int2(0, 0), metaB = make_int2(0, 0);
  uint2 rawA = make_uint2(0, 0), rawB = make_uint2(0, 0);
  if (e < e1) {
    metaA = eidx[e];
    rawA = *(const uint2*)&xlh[(size_t)metaA.x * 64 + cb];
  }
  if (e + 4 < e1) {
    metaB = eidx[e + 4];
    rawB = *(const uint2*)&xlh[(size_t)metaB.x * 64 + cb];
  }

  while (e < e1) {
    int2 cm = metaA;
    uint2 craw = rawA;
    metaA = metaB;
    rawA = rawB;
    int en2 = e + 8;
    if (en2 < e1) {  // prefetch 2 iterations ahead
      metaB = eidx[en2];
      rawB = *(const uint2*)&xlh[(size_t)metaB.x * 64 + cb];
    }
    F16U u0, u1; u0.u = craw.x; u1.u = craw.y;
    f16x2 xj01 = u0.v, xj23 = u1.v;
    float eav = __int_as_float(cm.y);
    _Float16 eah = (_Float16)eav;
    f16x2 ea2 = {eah, eah};
    f16x2 z01 = __builtin_elementwise_fma(ea2, we01, xi01 + xj01);
    f16x2 z23 = __builtin_elementwise_fma(ea2, we23, xi23 + xj23);
    f16x2 l01 = __builtin_elementwise_fma(
        c02, __builtin_elementwise_min(z01, zz), __builtin_elementwise_max(z01, zz));
    f16x2 l23 = __builtin_elementwise_fma(
        c02, __builtin_elementwise_min(z23, zz), __builtin_elementwise_max(z23, zz));
    float p = __builtin_amdgcn_fdot2(l01, at01,
              __builtin_amdgcn_fdot2(l23, at23, 0.f, false), false);
    #pragma unroll
    for (int off = 1; off < 16; off <<= 1) p += __shfl_xor(p, off, 64);
    if (p > m + RESCALE_THR) {
      float coef = __expf(m - p);
      s = fmaf(s, coef, 1.f);
      acc.x = fmaf(acc.x, coef, (float)xj01[0]);
      acc.y = fmaf(acc.y, coef, (float)xj01[1]);
      acc.z = fmaf(acc.z, coef, (float)xj23[0]);
      acc.w = fmaf(acc.w, coef, (float)xj23[1]);
      m = p;
    } else {
      float wgt = __expf(p - m);
      s += wgt;
      acc.x = fmaf(wgt, (float)xj01[0], acc.x);
      acc.y = fmaf(wgt, (float)xj01[1], acc.y);
      acc.z = fmaf(wgt, (float)xj23[0], acc.z);
      acc.w = fmaf(wgt, (float)xj23[1], acc.w);
    }
    e += 4;
  }

  #pragma unroll
  for (int off = 16; off <= 32; off <<= 1) {
    float mo = __shfl_xor(m, off, 64);
    float so = __shfl_xor(s, off, 64);
    float4 ao;
    ao.x = __shfl_xor(acc.x, off, 64);
    ao.y = __shfl_xor(acc.y, off, 64);
    ao.z = __shfl_xor(acc.z, off, 64);
    ao.w = __shfl_xor(acc.w, off, 64);
    float mn = fmaxf(m, mo);
    float cs = (m == -INFINITY) ? 0.f : __expf(m - mn);
    float co = (mo == -INFINITY) ? 0.f : __expf(mo - mn);
    s = s * cs + so * co;
    acc.x = acc.x * cs + ao.x * co;
    acc.y = acc.y * cs + ao.y * co;
    acc.z = acc.z * cs + ao.z * co;
    acc.w = acc.w * cs + ao.w * co;
    m = mn;
  }

  if (g == 0) {
    float inv = 1.0f / s;
    float o0 = acc.x * inv + bias[cb + 0];
    float o1 = acc.y * inv + bias[cb + 1];
    float o2 = acc.z * inv + bias[cb + 2];
    float o3 = acc.w * inv + bias[cb + 3];
    if constexpr (OUT_HALF) {
      F16U ua, ub;
      ua.v = (f16x2){(_Float16)o0, (_Float16)o1};
      ub.v = (f16x2){(_Float16)o2, (_Float16)o3};
      *(uint2*)&((_Float16*)outp)[(size_t)n * 64 + cb] = make_uint2(ua.u, ub.u);
    } else {
      *(float4*)&((float*)outp)[(size_t)n * 64 + cb] = make_float4(o0, o1, o2, o3);
    }
  }
}

// ---------------- launch ----------------

extern "C" void kernel_launch(void* const* d_in, const int* in_sizes, int n_in,
                              void* d_out, int out_size, void* d_ws, size_t ws_size,
                              hipStream_t stream) {
  const float* x    = (const float*)d_in[0];
  const int*   ei   = (const int*)d_in[1];
  const float* ea   = (const float*)d_in[2];
  const float* Wl0  = (const float*)d_in[3];
  const float* bl0  = (const float*)d_in[4];
  const float* Wr0  = (const float*)d_in[5];
  const float* br0  = (const float*)d_in[6];
  const float* We0  = (const float*)d_in[7];
  const float* att0 = (const float*)d_in[8];
  const float* bias0= (const float*)d_in[9];
  const float* Wl1  = (const float*)d_in[10];
  const float* bl1  = (const float*)d_in[11];
  const float* Wr1  = (const float*)d_in[12];
  const float* br1  = (const float*)d_in[13];
  const float* We1  = (const float*)d_in[14];
  const float* att1 = (const float*)d_in[15];
  const float* bias1= (const float*)d_in[16];

  const int N  = in_sizes[0] / 128;
  const int E  = in_sizes[1] / 2;
  const int ET = E + N;
  const int* src = ei;
  const int* dst = ei + E;
  const int nbk = (N + NPB - 1) >> NPB_SHIFT;

  char* w = (char*)d_ws;
  _Float16* xlh  = (_Float16*)w; w += (size_t)N * 64 * 2;  // fp16 gather table (src side)
  _Float16* xrh  = (_Float16*)w; w += (size_t)N * 64 * 2;  // fp16 table (dst side)
  _Float16* h1h  = (_Float16*)w; w += (size_t)N * 64 * 2;  // fp16 layer-0 output
  int*    row_ptr= (int*)w;    w += (size_t)(N + 2) * 4;
  int2*   eidx   = (int2*)w;   w += (size_t)ET * 8;
  int*    bcur   = (int*)w;    w += NBK_MAX * 4;
  // tmp aliases xlh+xrh (N*256 B = 12.8 MB >= nbk*BCAP*8 = 11.2 MB):
  // CSR build completes before layer-0 lin2 writes the tables.
  int2*   tmp    = (int2*)xlh;

  float* out = (float*)d_out;

  // ---- CSR build (fixed-cap buckets; same graph for both layers) ----
  {
    int nblk = 256;
    int chunk = (E + nblk - 1) / nblk;
    (void)hipMemsetAsync(bcur, 0, (size_t)nbk * 4, stream);
    k_scatter_agg<<<nblk, 1024, 0, stream>>>(src, dst, ea, E, nbk, chunk, bcur, tmp);
    k_bucket_to_csr<<<nbk, 256, 0, stream>>>(tmp, bcur, N, ET, eidx, row_ptr);
  }

  int nblk = (N + 63) / 64;
  // ---- layer 0: 128 -> 64 ----
  k_lin2_mfma<128, false><<<nblk, 256, 0, stream>>>(x, Wl0, bl0, Wr0, br0, xlh, xrh, N);
  k_gat_edge<true><<<N, 64, 0, stream>>>(xlh, xrh, row_ptr, eidx, We0, att0, bias0, h1h, N);
  // ---- layer 1: 64 -> 64 ----
  k_lin2_mfma<64, true><<<nblk, 256, 0, stream>>>(h1h, Wl1, bl1, Wr1, br1, xlh, xrh, N);
  k_gat_edge<false><<<N, 64, 0, stream>>>(xlh, xrh, row_ptr, eidx, We1, att1, bias1, out, N);
}